// Round 17
// baseline (1608.197 us; speedup 1.0000x reference)
//
#include <hip/hip_runtime.h>
#include <math.h>

#define T_LEN 16384
#define HDIM 200
#define NPOOL 16

typedef __bf16 v8bf __attribute__((ext_vector_type(8)));
typedef float v4f __attribute__((ext_vector_type(4)));

// ---- scratch in module-scope device globals: d_ws is never touched ----
__device__ float g_ca[T_LEN];
__device__ float g_cb[T_LEN];
__device__ float g_rw2s[NPOOL * HDIM];
__device__ float g_rw2e[NPOOL * HDIM];
__device__ float g_gates[4 * HDIM];
__device__ float g_h[HDIM];
__device__ float g_c[HDIM];
__device__ float g_ch[HDIM];
__device__ float g_cc[HDIM];
__device__ float g_rs[HDIM];
__device__ float g_re[HDIM];
__device__ int   g_ctrl[17];
// bf16 canonical staging (converted from f32 inputs each call)
__device__ __align__(16) unsigned short g_Ubf[T_LEN * 400];        // 13.1 MB
__device__ __align__(16) unsigned short g_w2bf[2][3200 * 416];     // cols 400..415 = 0
__device__ __align__(16) unsigned short g_w3bf[2][3200 * 224];     // cols 200..223 = 0
__device__ __align__(16) unsigned short g_w4a[2][16 * 448];        // [0..223]=w4[:,0:200]+0s, [224..447]=w4[:,200:400]+0s
// per-iteration intermediates, stride 224 (cols 200..223 zeroed once in cvt)
__device__ __align__(16) unsigned short g_m1[2][T_LEN * 224];      // 14.7 MB
__device__ __align__(16) unsigned short g_m2[2][T_LEN * 224];      // 14.7 MB

__device__ inline unsigned short f2bf(float f) {
    unsigned int u = __builtin_bit_cast(unsigned int, f);
    unsigned int r = u + 0x7FFFu + ((u >> 16) & 1u);
    return (unsigned short)(r >> 16);
}
__device__ inline v8bf zero8() {
    return __builtin_bit_cast(v8bf, make_uint4(0u, 0u, 0u, 0u));
}
__device__ inline int clampT(int v) {
    return v < 0 ? 0 : (v >= T_LEN ? T_LEN - 1 : v);
}

// ---------------- merged f32->bf16 conversions + pad-zero + init ----------
#define CU_CH   819200            // U: 16384*400/8
#define C2_CH   166400            // w2: 3200*52
#define C3_CH   89600             // w3: 3200*28
#define W4A_CH  1792              // w4a: 2*16*56
#define PZ_CH   196608            // m1/m2 pad cols: 2 bufs * 2 nets * 16384 * 3
#define TOT_CH  (CU_CH + 2*C2_CH + 2*C3_CH + W4A_CH + PZ_CH)

__device__ inline void cvt_chunk(const float* __restrict__ src, unsigned short* __restrict__ dst,
                                 int src_stride, int cpr, int ncc, int idx) {
    int r = idx / cpr, c = idx - r * cpr;
    unsigned short o[8] = {0, 0, 0, 0, 0, 0, 0, 0};
    if (c < ncc) {
        const float* s = src + r * src_stride + c * 8;
        float4 f0 = reinterpret_cast<const float4*>(s)[0];
        float4 f1 = reinterpret_cast<const float4*>(s)[1];
        o[0] = f2bf(f0.x); o[1] = f2bf(f0.y); o[2] = f2bf(f0.z); o[3] = f2bf(f0.w);
        o[4] = f2bf(f1.x); o[5] = f2bf(f1.y); o[6] = f2bf(f1.z); o[7] = f2bf(f1.w);
    }
    *reinterpret_cast<uint4*>(dst + r * (cpr * 8) + c * 8) = *reinterpret_cast<uint4*>(o);
}

__global__ void k_cvt_all(const float* __restrict__ U,
                          const float* __restrict__ s_w2, const float* __restrict__ e_w2,
                          const float* __restrict__ s_w3, const float* __restrict__ e_w3,
                          const float* __restrict__ s_w4, const float* __restrict__ e_w4) {
    int i = blockIdx.x * 256 + threadIdx.x;
    if (i < CU_CH) { cvt_chunk(U, g_Ubf, 400, 50, 50, i); return; }
    i -= CU_CH;
    if (i < C2_CH) { cvt_chunk(s_w2, g_w2bf[0], 600, 52, 50, i); return; }
    i -= C2_CH;
    if (i < C2_CH) { cvt_chunk(e_w2, g_w2bf[1], 600, 52, 50, i); return; }
    i -= C2_CH;
    if (i < C3_CH) { cvt_chunk(s_w3, g_w3bf[0], 200, 28, 25, i); return; }
    i -= C3_CH;
    if (i < C3_CH) { cvt_chunk(e_w3, g_w3bf[1], 200, 28, 25, i); return; }
    i -= C3_CH;
    if (i < W4A_CH) {
        int net = i / 896, rem = i - net * 896;
        int r = rem / 56, c = rem - r * 56;
        const float* src = net ? e_w4 : s_w4;
        unsigned short o[8];
#pragma unroll
        for (int j = 0; j < 8; j++) {
            int k = c * 8 + j;
            float v = 0.f;
            if (k < 200) v = src[r * 400 + k];
            else if (k >= 224 && k < 424) v = src[r * 400 + (k - 24)];
            o[j] = f2bf(v);
        }
        *reinterpret_cast<uint4*>(&g_w4a[net][r * 448 + c * 8]) = *reinterpret_cast<uint4*>(o);
        return;
    }
    i -= W4A_CH;
    if (i < PZ_CH) {
        int buf = i / 98304, rem = i - buf * 98304;
        int net = rem / 49152, rem2 = rem - net * 49152;
        int row = rem2 / 3, c = rem2 - row * 3;
        unsigned short* dst = (buf ? g_m2[net] : g_m1[net]) + row * 224 + 200 + c * 8;
        *reinterpret_cast<uint4*>(dst) = make_uint4(0u, 0u, 0u, 0u);
        return;
    }
    i -= PZ_CH;
    if (i < HDIM) { g_h[i] = 0.f; g_c[i] = 0.f; return; }
    i -= HDIM;
    if (i == 0) { g_ctrl[0] = 0; g_ctrl[1] = 0; g_ctrl[2] = 0; }
}

// ---------------- gates = x@Wih.T + h@Whh.T + bih + bhh  (800 rows) -------
__global__ void k_gates(const float* __restrict__ U,
                        const float* __restrict__ Wih,
                        const float* __restrict__ Whh,
                        const float* __restrict__ bih,
                        const float* __restrict__ bhh,
                        int k) {
    int row = blockIdx.x * 16 + (threadIdx.x >> 4);
    int l = threadIdx.x & 15;
    int start = clampT(g_ctrl[k * 3 + 0]), end = clampT(g_ctrl[k * 3 + 1]);
    float sum = 0.f;
    for (int j = l; j < 800; j += 16) {
        float xv = (j < 400) ? U[start * 400 + j] : U[end * 400 + (j - 400)];
        sum += Wih[row * 800 + j] * xv;
    }
    for (int j = l; j < HDIM; j += 16)
        sum += Whh[row * HDIM + j] * g_h[j];
    for (int off = 8; off > 0; off >>= 1) sum += __shfl_xor(sum, off, 16);
    if (l == 0) g_gates[row] = sum + bih[row] + bhh[row];
}

// ------- r = tanh([ch, U[s], U[e]] @ w1.T), hc computed inline (per block) -
__global__ void k_r(const float* __restrict__ U,
                    const float* __restrict__ s_w1,
                    const float* __restrict__ e_w1,
                    int k) {
    __shared__ float ch_s[HDIM];
    int t = threadIdx.x;
    if (t < HDIM) {
        float gi = g_gates[t], gf = g_gates[HDIM + t];
        float gg = g_gates[2 * HDIM + t], go = g_gates[3 * HDIM + t];
        float si = 1.f / (1.f + expf(-gi));
        float sf = 1.f / (1.f + expf(-gf));
        float so = 1.f / (1.f + expf(-go));
        float tg = tanhf(gg);
        float cn = sf * g_c[t] + si * tg;
        float hv = so * tanhf(cn);
        ch_s[t] = hv;
        if (blockIdx.x == 0) { g_ch[t] = hv; g_cc[t] = cn; }
    }
    __syncthreads();
    int g = blockIdx.x * 16 + (threadIdx.x >> 4);
    int l = threadIdx.x & 15;
    int net = g / HDIM, i = g % HDIM;
    const float* w1 = net ? e_w1 : s_w1;
    int start = clampT(g_ctrl[k * 3 + 0]), end = clampT(g_ctrl[k * 3 + 1]);
    float sum = 0.f;
    for (int j = l; j < 1000; j += 16) {
        float cv;
        if (j < 200) cv = ch_s[j];
        else if (j < 600) cv = U[start * 400 + (j - 200)];
        else cv = U[end * 400 + (j - 600)];
        sum += w1[i * 1000 + j] * cv;
    }
    for (int off = 8; off > 0; off >>= 1) sum += __shfl_xor(sum, off, 16);
    if (l == 0) { float* out = net ? g_re : g_rs; out[i] = tanhf(sum); }
}

// ---------------- rw2 = r @ w2[:,400:].T + b2  (3200 each net) ------------
__global__ void k_rw2(const float* __restrict__ s_w2,
                      const float* __restrict__ s_b2,
                      const float* __restrict__ e_w2,
                      const float* __restrict__ e_b2) {
    int g = blockIdx.x * 16 + (threadIdx.x >> 4);
    int l = threadIdx.x & 15;
    int net = g / 3200, n = g % 3200;
    const float* w2 = net ? e_w2 : s_w2;
    const float* b2 = net ? e_b2 : s_b2;
    const float* r = net ? g_re : g_rs;
    float sum = 0.f;
    for (int j = l; j < HDIM; j += 16)
        sum += w2[n * 600 + 400 + j] * r[j];
    for (int off = 8; off > 0; off >>= 1) sum += __shfl_xor(sum, off, 16);
    if (l == 0) { float* out = net ? g_rw2e : g_rw2s; out[n] = sum + b2[n]; }
}

// ---------------- k_m1: m1 = maxpool_p(U @ w2a.T + rw2) -> g_m1 -----------
// R17: NO LDS, NO BARRIERS. R16 counters showed occupancy is register-bound
// (A-frags ~104 AGPR + 80 VGPR -> 2 waves/SIMD) and the per-tile cost is the
// SUM of LDS reads + staging + barrier-drain serialization. B traffic at 32
// rows/wave + jt-thirds is only ~178 MB/dispatch (trivial for L2), so B-frags
// are loaded DIRECTLY from global into registers; the compiler's per-use
// vmcnt pipelines loads behind MFMAs with no barrier fence. Blocks = 4 waves
// of the SAME (net,third), different 32-row groups -> B reads are L1-shared.
// grid 768 x 256. XCD pin: net=(bid>>2)&1 under bid%8 round-robin.
__global__ __launch_bounds__(256, 2) void k_m1() {
    const int bid = blockIdx.x;
    const int net = (bid >> 2) & 1;
    const int r = (bid >> 3) * 4 + (bid & 3);   // 0..383
    const int third = r % 3;
    const int m0 = (r / 3) * 128;
    const unsigned short* w2 = g_w2bf[net];
    const float* rw2 = net ? g_rw2e : g_rw2s;
    unsigned short* m1o = g_m1[net];
    const int tid = threadIdx.x;
    const int lane = tid & 63, wave = tid >> 6;  // 0..3
    const int q = lane >> 4, col = lane & 15, qo = q * 8;
    const int rowb = m0 + wave * 32;
    const int njt = (third == 0) ? 5 : 4;

    // A-frags direct from global; mask ks==12&&q>=2 (U row len 400; B pad=0)
    v8bf a1[2][13];
#pragma unroll
    for (int s = 0; s < 2; s++) {
        const unsigned short* ap = g_Ubf + (rowb + s * 16 + col) * 400 + qo;
#pragma unroll
        for (int ks = 0; ks < 13; ks++) {
            if (ks < 12 || q < 2) a1[s][ks] = *reinterpret_cast<const v8bf*>(ap + ks * 32);
            else a1[s][ks] = zero8();
        }
    }

    for (int jc = 0; jc < njt; jc++) {
        const int jt = jc * 3 + third;
        const int j0 = (jt < 12) ? jt * 16 : 184;
        const int n = j0 + col;
        const unsigned short* wb = w2 + n * 416 + qo;
        v4f mx0 = {-INFINITY, -INFINITY, -INFINITY, -INFINITY};
        v4f mx1 = mx0;
#pragma unroll 1
        for (int p = 0; p < NPOOL; p++) {
            const unsigned short* bp = wb + p * (HDIM * 416);
            v8bf b[13];
#pragma unroll
            for (int ks = 0; ks < 13; ks++)
                b[ks] = *reinterpret_cast<const v8bf*>(bp + ks * 32);
            v4f a00 = {0.f, 0.f, 0.f, 0.f}, a01 = a00, a10 = a00, a11 = a00;
#pragma unroll
            for (int ks = 0; ks < 12; ks += 2) {
                a00 = __builtin_amdgcn_mfma_f32_16x16x32_bf16(a1[0][ks], b[ks], a00, 0, 0, 0);
                a10 = __builtin_amdgcn_mfma_f32_16x16x32_bf16(a1[1][ks], b[ks], a10, 0, 0, 0);
                a01 = __builtin_amdgcn_mfma_f32_16x16x32_bf16(a1[0][ks + 1], b[ks + 1], a01, 0, 0, 0);
                a11 = __builtin_amdgcn_mfma_f32_16x16x32_bf16(a1[1][ks + 1], b[ks + 1], a11, 0, 0, 0);
            }
            a00 = __builtin_amdgcn_mfma_f32_16x16x32_bf16(a1[0][12], b[12], a00, 0, 0, 0);
            a10 = __builtin_amdgcn_mfma_f32_16x16x32_bf16(a1[1][12], b[12], a10, 0, 0, 0);
            float rv = rw2[p * HDIM + n];
#pragma unroll
            for (int i = 0; i < 4; i++) {
                mx0[i] = fmaxf(mx0[i], a00[i] + a01[i] + rv);
                mx1[i] = fmaxf(mx1[i], a10[i] + a11[i] + rv);
            }
        }
#pragma unroll
        for (int i = 0; i < 4; i++) {
            m1o[(rowb + q * 4 + i) * 224 + n] = f2bf(mx0[i]);
            m1o[(rowb + 16 + q * 4 + i) * 224 + n] = f2bf(mx1[i]);
        }
    }
}

// ---------------- k_m2: m2 = maxpool_p(m1 @ w3.T + b3) -> g_m2 ------------
// Same no-LDS/no-barrier structure; A = g_m1 (stride 224, zero pads ->
// exact K=224, no masks).
__global__ __launch_bounds__(256, 2) void k_m2(
    const float* __restrict__ b3s, const float* __restrict__ b3e) {
    const int bid = blockIdx.x;
    const int net = (bid >> 2) & 1;
    const int r = (bid >> 3) * 4 + (bid & 3);
    const int third = r % 3;
    const int m0 = (r / 3) * 128;
    const unsigned short* w3 = g_w3bf[net];
    const float* b3 = net ? b3e : b3s;
    unsigned short* m2o = g_m2[net];
    const int tid = threadIdx.x;
    const int lane = tid & 63, wave = tid >> 6;
    const int q = lane >> 4, col = lane & 15, qo = q * 8;
    const int rowb = m0 + wave * 32;
    const int njt = (third == 0) ? 5 : 4;

    v8bf a2[2][7];
#pragma unroll
    for (int s = 0; s < 2; s++) {
        const unsigned short* ap = g_m1[net] + (rowb + s * 16 + col) * 224 + qo;
#pragma unroll
        for (int ks = 0; ks < 7; ks++)
            a2[s][ks] = *reinterpret_cast<const v8bf*>(ap + ks * 32);
    }

    for (int jc = 0; jc < njt; jc++) {
        const int jt = jc * 3 + third;
        const int j0 = (jt < 12) ? jt * 16 : 184;
        const int n = j0 + col;
        const unsigned short* wb = w3 + n * 224 + qo;
        v4f mx0 = {-INFINITY, -INFINITY, -INFINITY, -INFINITY};
        v4f mx1 = mx0;
#pragma unroll 1
        for (int p = 0; p < NPOOL; p++) {
            const unsigned short* bp = wb + p * (HDIM * 224);
            v8bf b[7];
#pragma unroll
            for (int ks = 0; ks < 7; ks++)
                b[ks] = *reinterpret_cast<const v8bf*>(bp + ks * 32);
            v4f a00 = {0.f, 0.f, 0.f, 0.f}, a01 = a00, a10 = a00, a11 = a00;
#pragma unroll
            for (int ks = 0; ks < 6; ks += 2) {
                a00 = __builtin_amdgcn_mfma_f32_16x16x32_bf16(a2[0][ks], b[ks], a00, 0, 0, 0);
                a10 = __builtin_amdgcn_mfma_f32_16x16x32_bf16(a2[1][ks], b[ks], a10, 0, 0, 0);
                a01 = __builtin_amdgcn_mfma_f32_16x16x32_bf16(a2[0][ks + 1], b[ks + 1], a01, 0, 0, 0);
                a11 = __builtin_amdgcn_mfma_f32_16x16x32_bf16(a2[1][ks + 1], b[ks + 1], a11, 0, 0, 0);
            }
            a00 = __builtin_amdgcn_mfma_f32_16x16x32_bf16(a2[0][6], b[6], a00, 0, 0, 0);
            a10 = __builtin_amdgcn_mfma_f32_16x16x32_bf16(a2[1][6], b[6], a10, 0, 0, 0);
            float bv = b3[p * HDIM + n];
#pragma unroll
            for (int i = 0; i < 4; i++) {
                mx0[i] = fmaxf(mx0[i], a00[i] + a01[i] + bv);
                mx1[i] = fmaxf(mx1[i], a10[i] + a11[i] + bv);
            }
        }
#pragma unroll
        for (int i = 0; i < 4; i++) {
            m2o[(rowb + q * 4 + i) * 224 + n] = f2bf(mx0[i]);
            m2o[(rowb + 16 + q * 4 + i) * 224 + n] = f2bf(mx1[i]);
        }
    }
}

// ---------------- k_alpha: max_n([m1|m2] @ w4.T + b4) -> ca/cb ------------
__global__ __launch_bounds__(128) void k_alpha(
    const float* __restrict__ b4s, const float* __restrict__ b4e) {
    const int bid = blockIdx.x;
    const int net = (bid >> 2) & 1;
    const int m0 = ((bid >> 3) * 4 + (bid & 3)) * 64;
    const unsigned short* w4 = g_w4a[net];
    const float* b4 = net ? b4e : b4s;
    float* outv = net ? g_cb : g_ca;
    const int tid = threadIdx.x;
    const int lane = tid & 63, wave = tid >> 6;
    const int q = lane >> 4, col = lane & 15, qo = q * 8;
    const int rowb = m0 + wave * 32;

    v4f ac0 = {0.f, 0.f, 0.f, 0.f}, ac1 = ac0;
#pragma unroll
    for (int half = 0; half < 2; half++) {
        const unsigned short* src = half ? g_m2[net] : g_m1[net];
#pragma unroll
        for (int ks = 0; ks < 7; ks++) {
            v8bf b = *reinterpret_cast<const v8bf*>(&w4[col * 448 + half * 224 + ks * 32 + qo]);
            v8bf x0 = *reinterpret_cast<const v8bf*>(src + (rowb + col) * 224 + ks * 32 + qo);
            ac0 = __builtin_amdgcn_mfma_f32_16x16x32_bf16(x0, b, ac0, 0, 0, 0);
            v8bf x1 = *reinterpret_cast<const v8bf*>(src + (rowb + 16 + col) * 224 + ks * 32 + qo);
            ac1 = __builtin_amdgcn_mfma_f32_16x16x32_bf16(x1, b, ac1, 0, 0, 0);
        }
    }
    float bbi = b4[col];
#pragma unroll
    for (int s = 0; s < 2; s++) {
        v4f ac = s ? ac1 : ac0;
        float v0 = ac[0] + bbi, v1 = ac[1] + bbi, v2 = ac[2] + bbi, v3 = ac[3] + bbi;
        for (int off = 1; off < 16; off <<= 1) {
            v0 = fmaxf(v0, __shfl_xor(v0, off, 16));
            v1 = fmaxf(v1, __shfl_xor(v1, off, 16));
            v2 = fmaxf(v2, __shfl_xor(v2, off, 16));
            v3 = fmaxf(v3, __shfl_xor(v3, off, 16));
        }
        if (col == 0) {
            const int tb = rowb + s * 16 + q * 4;
            outv[tb + 0] = v0;
            outv[tb + 1] = v1;
            outv[tb + 2] = v2;
            outv[tb + 3] = v3;
        }
    }
}

// -------- commit (+inline argmax in block 128): freeze-select & advance ---
__global__ void k_commit(int k, float* __restrict__ out) {
    int done = g_ctrl[k * 3 + 2];
    if (blockIdx.x < 128) {
        int is_beta = blockIdx.x >= 64;
        int t = ((int)blockIdx.x & 63) * 256 + threadIdx.x;
        float* row = out + (is_beta ? 4 * T_LEN : 0) + k * T_LEN;
        if (done) row[t] = row[t - T_LEN];
        else row[t] = (is_beta ? g_cb : g_ca)[t];
    } else {
        __shared__ float sv[256];
        __shared__ int si[256];
        int ns = 0, ne = 0;
        for (int which = 0; which < 2; which++) {
            const float* src = which ? g_cb : g_ca;
            float best = -INFINITY;
            int bi = T_LEN - 1;
            for (int t = threadIdx.x; t < T_LEN; t += 256) {
                float v = src[t];
                if (v > best) { best = v; bi = t; }
            }
            sv[threadIdx.x] = best; si[threadIdx.x] = bi;
            __syncthreads();
            for (int s = 128; s > 0; s >>= 1) {
                if (threadIdx.x < s) {
                    float ov = sv[threadIdx.x + s]; int oi = si[threadIdx.x + s];
                    if (ov > sv[threadIdx.x] || (ov == sv[threadIdx.x] && oi < si[threadIdx.x])) {
                        sv[threadIdx.x] = ov; si[threadIdx.x] = oi;
                    }
                }
                __syncthreads();
            }
            if (which == 0) ns = clampT(si[0]); else ne = clampT(si[0]);
            __syncthreads();
        }
        int t = threadIdx.x;
        if (t < HDIM && !done) { g_h[t] = g_ch[t]; g_c[t] = g_cc[t]; }
        if (t == 0) {
            int sp = g_ctrl[k * 3 + 0], ep = g_ctrl[k * 3 + 1];
            if (done) {
                g_ctrl[(k + 1) * 3 + 0] = sp;
                g_ctrl[(k + 1) * 3 + 1] = ep;
                g_ctrl[(k + 1) * 3 + 2] = 1;
            } else {
                g_ctrl[(k + 1) * 3 + 0] = ns;
                g_ctrl[(k + 1) * 3 + 1] = ne;
                g_ctrl[(k + 1) * 3 + 2] = (k == 0) ? 0 : ((ns == sp && ne == ep) ? 1 : 0);
            }
        }
    }
}

extern "C" void kernel_launch(void* const* d_in, const int* in_sizes, int n_in,
                              void* d_out, int out_size, void* d_ws, size_t ws_size,
                              hipStream_t stream) {
    const float* U    = (const float*)d_in[0];
    const float* Wih  = (const float*)d_in[1];
    const float* Whh  = (const float*)d_in[2];
    const float* bih  = (const float*)d_in[3];
    const float* bhh  = (const float*)d_in[4];
    const float* s_w1 = (const float*)d_in[5];
    const float* s_w2 = (const float*)d_in[6];
    const float* s_b2 = (const float*)d_in[7];
    const float* s_w3 = (const float*)d_in[8];
    const float* s_b3 = (const float*)d_in[9];
    const float* s_w4 = (const float*)d_in[10];
    const float* s_b4 = (const float*)d_in[11];
    const float* e_w1 = (const float*)d_in[12];
    const float* e_w2 = (const float*)d_in[13];
    const float* e_b2 = (const float*)d_in[14];
    const float* e_w3 = (const float*)d_in[15];
    const float* e_b3 = (const float*)d_in[16];
    const float* e_w4 = (const float*)d_in[17];
    const float* e_b4 = (const float*)d_in[18];
    float* out = (float*)d_out;
    (void)d_ws; (void)ws_size; (void)in_sizes; (void)n_in; (void)out_size;

    const int cvt_blocks = (TOT_CH + HDIM + 1 + 255) / 256;
    k_cvt_all<<<cvt_blocks, 256, 0, stream>>>(U, s_w2, e_w2, s_w3, e_w3, s_w4, e_w4);

    for (int k = 0; k < 4; k++) {
        k_gates<<<50, 256, 0, stream>>>(U, Wih, Whh, bih, bhh, k);
        k_r<<<25, 256, 0, stream>>>(U, s_w1, e_w1, k);
        k_rw2<<<400, 256, 0, stream>>>(s_w2, s_b2, e_w2, e_b2);
        k_m1<<<768, 256, 0, stream>>>();
        k_m2<<<768, 256, 0, stream>>>(s_b3, e_b3);
        k_alpha<<<512, 128, 0, stream>>>(s_b4, e_b4);
        k_commit<<<129, 256, 0, stream>>>(k, out);
    }
}

// Round 18
// 1087.392 us; speedup vs baseline: 1.4789x; 1.4789x over previous
//
#include <hip/hip_runtime.h>
#include <math.h>

#define T_LEN 16384
#define HDIM 200
#define NPOOL 16

typedef __bf16 v8bf __attribute__((ext_vector_type(8)));
typedef float v4f __attribute__((ext_vector_type(4)));

// ---- scratch in module-scope device globals: d_ws is never touched ----
__device__ float g_ca[T_LEN];
__device__ float g_cb[T_LEN];
__device__ float g_rw2s[NPOOL * HDIM];
__device__ float g_rw2e[NPOOL * HDIM];
__device__ __align__(16) float g_gates[4 * HDIM];
__device__ __align__(16) float g_h[HDIM];
__device__ __align__(16) float g_c[HDIM];
__device__ __align__(16) float g_ch[HDIM];
__device__ __align__(16) float g_cc[HDIM];
__device__ __align__(16) float g_rs[HDIM];
__device__ __align__(16) float g_re[HDIM];
__device__ int   g_ctrl[17];
// bf16 canonical staging (converted from f32 inputs each call)
__device__ __align__(16) unsigned short g_Ubf[T_LEN * 400];        // 13.1 MB
__device__ __align__(16) unsigned short g_w2bf[2][3200 * 416];     // cols 400..415 = 0
__device__ __align__(16) unsigned short g_w3bf[2][3200 * 224];     // cols 200..223 = 0
__device__ __align__(16) unsigned short g_w4a[2][16 * 448];        // [0..223]=w4[:,0:200]+0s, [224..447]=w4[:,200:400]+0s
// per-iteration intermediates, stride 224 (cols 200..223 zeroed once in cvt)
__device__ __align__(16) unsigned short g_m1[2][T_LEN * 224];      // 14.7 MB
__device__ __align__(16) unsigned short g_m2[2][T_LEN * 224];      // 14.7 MB

__device__ inline unsigned short f2bf(float f) {
    unsigned int u = __builtin_bit_cast(unsigned int, f);
    unsigned int r = u + 0x7FFFu + ((u >> 16) & 1u);
    return (unsigned short)(r >> 16);
}
__device__ inline v8bf zero8() {
    return __builtin_bit_cast(v8bf, make_uint4(0u, 0u, 0u, 0u));
}
__device__ inline int clampT(int v) {
    return v < 0 ? 0 : (v >= T_LEN ? T_LEN - 1 : v);
}
__device__ inline float dot4(float4 a, float4 b) {
    return fmaf(a.x, b.x, fmaf(a.y, b.y, fmaf(a.z, b.z, a.w * b.w)));
}

// async global->LDS, 16B per lane; LDS dest = wave-uniform base + lane*16
__device__ inline void gl_lds16(const unsigned short* g, unsigned short* l) {
    __builtin_amdgcn_global_load_lds(
        (const __attribute__((address_space(1))) unsigned int*)g,
        (__attribute__((address_space(3))) unsigned int*)l,
        16, 0, 0);
}

// ---------------- merged f32->bf16 conversions + pad-zero + init ----------
#define CU_CH   819200            // U: 16384*400/8
#define C2_CH   166400            // w2: 3200*52
#define C3_CH   89600             // w3: 3200*28
#define W4A_CH  1792              // w4a: 2*16*56
#define PZ_CH   196608            // m1/m2 pad cols: 2 bufs * 2 nets * 16384 * 3
#define TOT_CH  (CU_CH + 2*C2_CH + 2*C3_CH + W4A_CH + PZ_CH)

__device__ inline void cvt_chunk(const float* __restrict__ src, unsigned short* __restrict__ dst,
                                 int src_stride, int cpr, int ncc, int idx) {
    int r = idx / cpr, c = idx - r * cpr;
    unsigned short o[8] = {0, 0, 0, 0, 0, 0, 0, 0};
    if (c < ncc) {
        const float* s = src + r * src_stride + c * 8;
        float4 f0 = reinterpret_cast<const float4*>(s)[0];
        float4 f1 = reinterpret_cast<const float4*>(s)[1];
        o[0] = f2bf(f0.x); o[1] = f2bf(f0.y); o[2] = f2bf(f0.z); o[3] = f2bf(f0.w);
        o[4] = f2bf(f1.x); o[5] = f2bf(f1.y); o[6] = f2bf(f1.z); o[7] = f2bf(f1.w);
    }
    *reinterpret_cast<uint4*>(dst + r * (cpr * 8) + c * 8) = *reinterpret_cast<uint4*>(o);
}

__global__ void k_cvt_all(const float* __restrict__ U,
                          const float* __restrict__ s_w2, const float* __restrict__ e_w2,
                          const float* __restrict__ s_w3, const float* __restrict__ e_w3,
                          const float* __restrict__ s_w4, const float* __restrict__ e_w4) {
    int i = blockIdx.x * 256 + threadIdx.x;
    if (i < CU_CH) { cvt_chunk(U, g_Ubf, 400, 50, 50, i); return; }
    i -= CU_CH;
    if (i < C2_CH) { cvt_chunk(s_w2, g_w2bf[0], 600, 52, 50, i); return; }
    i -= C2_CH;
    if (i < C2_CH) { cvt_chunk(e_w2, g_w2bf[1], 600, 52, 50, i); return; }
    i -= C2_CH;
    if (i < C3_CH) { cvt_chunk(s_w3, g_w3bf[0], 200, 28, 25, i); return; }
    i -= C3_CH;
    if (i < C3_CH) { cvt_chunk(e_w3, g_w3bf[1], 200, 28, 25, i); return; }
    i -= C3_CH;
    if (i < W4A_CH) {
        int net = i / 896, rem = i - net * 896;
        int r = rem / 56, c = rem - r * 56;
        const float* src = net ? e_w4 : s_w4;
        unsigned short o[8];
#pragma unroll
        for (int j = 0; j < 8; j++) {
            int k = c * 8 + j;
            float v = 0.f;
            if (k < 200) v = src[r * 400 + k];
            else if (k >= 224 && k < 424) v = src[r * 400 + (k - 24)];
            o[j] = f2bf(v);
        }
        *reinterpret_cast<uint4*>(&g_w4a[net][r * 448 + c * 8]) = *reinterpret_cast<uint4*>(o);
        return;
    }
    i -= W4A_CH;
    if (i < PZ_CH) {
        int buf = i / 98304, rem = i - buf * 98304;
        int net = rem / 49152, rem2 = rem - net * 49152;
        int row = rem2 / 3, c = rem2 - row * 3;
        unsigned short* dst = (buf ? g_m2[net] : g_m1[net]) + row * 224 + 200 + c * 8;
        *reinterpret_cast<uint4*>(dst) = make_uint4(0u, 0u, 0u, 0u);
        return;
    }
    i -= PZ_CH;
    if (i < HDIM) { g_h[i] = 0.f; g_c[i] = 0.f; return; }
    i -= HDIM;
    if (i == 0) { g_ctrl[0] = 0; g_ctrl[1] = 0; g_ctrl[2] = 0; }
}

// ------- gates = x@Wih.T + h@Whh.T + biases (800 rows, float4 coalesced) --
__global__ void k_gates(const float* __restrict__ U,
                        const float* __restrict__ Wih,
                        const float* __restrict__ Whh,
                        const float* __restrict__ bih,
                        const float* __restrict__ bhh,
                        int k) {
    int row = blockIdx.x * 16 + (threadIdx.x >> 4);
    int l = threadIdx.x & 15;
    int start = clampT(g_ctrl[k * 3 + 0]), end = clampT(g_ctrl[k * 3 + 1]);
    const float4* W4 = reinterpret_cast<const float4*>(Wih) + row * 200;
    const float4* Us = reinterpret_cast<const float4*>(U + start * 400);
    const float4* Ue = reinterpret_cast<const float4*>(U + end * 400);
    float sum = 0.f;
    for (int c = l; c < 200; c += 16) {
        float4 xv = (c < 100) ? Us[c] : Ue[c - 100];
        sum += dot4(W4[c], xv);
    }
    const float4* Wh4 = reinterpret_cast<const float4*>(Whh) + row * 50;
    const float4* h4 = reinterpret_cast<const float4*>(g_h);
    for (int c = l; c < 50; c += 16)
        sum += dot4(Wh4[c], h4[c]);
    for (int off = 8; off > 0; off >>= 1) sum += __shfl_xor(sum, off, 16);
    if (l == 0) g_gates[row] = sum + bih[row] + bhh[row];
}

// ------- r = tanh([ch, U[s], U[e]] @ w1.T), hc inline, float4 coalesced ---
__global__ void k_r(const float* __restrict__ U,
                    const float* __restrict__ s_w1,
                    const float* __restrict__ e_w1,
                    int k) {
    __shared__ __align__(16) float ch_s[HDIM];
    int t = threadIdx.x;
    if (t < HDIM) {
        float gi = g_gates[t], gf = g_gates[HDIM + t];
        float gg = g_gates[2 * HDIM + t], go = g_gates[3 * HDIM + t];
        float si = 1.f / (1.f + expf(-gi));
        float sf = 1.f / (1.f + expf(-gf));
        float so = 1.f / (1.f + expf(-go));
        float tg = tanhf(gg);
        float cn = sf * g_c[t] + si * tg;
        float hv = so * tanhf(cn);
        ch_s[t] = hv;
        if (blockIdx.x == 0) { g_ch[t] = hv; g_cc[t] = cn; }
    }
    __syncthreads();
    int g = blockIdx.x * 16 + (threadIdx.x >> 4);
    int l = threadIdx.x & 15;
    int net = g / HDIM, i = g % HDIM;
    const float* w1 = net ? e_w1 : s_w1;
    int start = clampT(g_ctrl[k * 3 + 0]), end = clampT(g_ctrl[k * 3 + 1]);
    const float4* w14 = reinterpret_cast<const float4*>(w1) + i * 250;
    const float4* c4 = reinterpret_cast<const float4*>(ch_s);
    const float4* Us = reinterpret_cast<const float4*>(U + start * 400);
    const float4* Ue = reinterpret_cast<const float4*>(U + end * 400);
    float sum = 0.f;
    for (int c = l; c < 250; c += 16) {
        float4 cv;
        if (c < 50) cv = c4[c];
        else if (c < 150) cv = Us[c - 50];
        else cv = Ue[c - 150];
        sum += dot4(w14[c], cv);
    }
    for (int off = 8; off > 0; off >>= 1) sum += __shfl_xor(sum, off, 16);
    if (l == 0) { float* out = net ? g_re : g_rs; out[i] = tanhf(sum); }
}

// ------- rw2 = r @ w2[:,400:].T + b2 (3200 each net), float4 coalesced ----
__global__ void k_rw2(const float* __restrict__ s_w2,
                      const float* __restrict__ s_b2,
                      const float* __restrict__ e_w2,
                      const float* __restrict__ e_b2) {
    int g = blockIdx.x * 16 + (threadIdx.x >> 4);
    int l = threadIdx.x & 15;
    int net = g / 3200, n = g % 3200;
    const float* w2 = net ? e_w2 : s_w2;
    const float* b2 = net ? e_b2 : s_b2;
    const float4* r4 = reinterpret_cast<const float4*>(net ? g_re : g_rs);
    const float4* w24 = reinterpret_cast<const float4*>(w2) + n * 150 + 100;
    float sum = 0.f;
    for (int c = l; c < 50; c += 16)
        sum += dot4(w24[c], r4[c]);
    for (int off = 8; off > 0; off >>= 1) sum += __shfl_xor(sum, off, 16);
    if (l == 0) { float* out = net ? g_rw2e : g_rw2s; out[n] = sum + b2[n]; }
}

// ---------------- k_m1: m1 = maxpool_p(U @ w2a.T + rw2) -> g_m1 -----------
// R18: R16's LDS pipeline, but 128-row blocks (4 waves x 32 rows) share ONE
// staged B-tile -> staging bytes and barrier count per unit work HALVE vs
// R16. jt-HALVES (half h: jt = h, h+2, ...), grid 512 = exactly 2 blk/CU
// (reg-bound 2 waves/SIMD: a1 ~104 AGPR + ~80 VGPR). LDS 26,624 B/block.
// Tile t: jt=(t>>4)*2+half, p=t&15. XCD pin: net=(bid>>2)&1 under bid%8.
__global__ __launch_bounds__(256, 2) void k_m1() {
    const int bid = blockIdx.x;
    const int net = (bid >> 2) & 1;
    const int r = (bid >> 3) * 4 + (bid & 3);   // 0..255
    const int half = r & 1;
    const int m0 = (r >> 1) * 128;
    const unsigned short* w2 = g_w2bf[net];
    const float* rw2 = net ? g_rw2e : g_rw2s;
    unsigned short* m1o = g_m1[net];
    __shared__ __align__(16) unsigned short Bs[2][6656];
    const int tid = threadIdx.x;
    const int lane = tid & 63, wave = tid >> 6;  // 0..3
    const int q = lane >> 4, col = lane & 15, qo = q * 8;
    const int rowb = m0 + wave * 32;
    const int njt = half ? 6 : 7;
    const int T2 = njt * 16;

    // A-frags direct from global; mask ks==12&&q>=2 (U row len 400; B pad=0)
    v8bf a1[2][13];
#pragma unroll
    for (int s = 0; s < 2; s++) {
        const unsigned short* ap = g_Ubf + (rowb + s * 16 + col) * 400 + qo;
#pragma unroll
        for (int ks = 0; ks < 13; ks++) {
            if (ks < 12 || q < 2) a1[s][ks] = *reinterpret_cast<const v8bf*>(ap + ks * 32);
            else a1[s][ks] = zero8();
        }
    }
    {   // prologue: stage tile 0 (jt=half, p=0); 4-wave chunk split
        const unsigned short* gb = w2 + (half * 16 + col) * 416 + qo;
        for (int c = wave; c < 13; c += 4) gl_lds16(gb + c * 32, &Bs[0][c * 512]);
    }
    v4f mx0, mx1;
    for (int t = 0; t < T2; t++) {
        __syncthreads();  // drains stage(t) (vmcnt before barrier)
        if (t + 1 < T2) {
            int jtn = ((t + 1) >> 4) * 2 + half, pn = (t + 1) & 15;
            int j0n = (jtn < 12) ? jtn * 16 : 184;
            const unsigned short* gb = w2 + (pn * HDIM + j0n + col) * 416 + qo;
            unsigned short* lb = Bs[(t + 1) & 1];
            for (int c = wave; c < 13; c += 4) gl_lds16(gb + c * 32, lb + c * 512);
        }
        const unsigned short* bb = Bs[t & 1];
        int jt = (t >> 4) * 2 + half, p = t & 15;
        int j0 = (jt < 12) ? jt * 16 : 184;
        int n = j0 + col;
        if (p == 0) {
            mx0 = (v4f){-INFINITY, -INFINITY, -INFINITY, -INFINITY};
            mx1 = mx0;
        }
        v4f a00 = {0.f, 0.f, 0.f, 0.f}, a01 = a00, a10 = a00, a11 = a00;
#pragma unroll
        for (int ks = 0; ks < 12; ks += 2) {
            v8bf b0 = *reinterpret_cast<const v8bf*>(&bb[ks * 512 + lane * 8]);
            a00 = __builtin_amdgcn_mfma_f32_16x16x32_bf16(a1[0][ks], b0, a00, 0, 0, 0);
            a10 = __builtin_amdgcn_mfma_f32_16x16x32_bf16(a1[1][ks], b0, a10, 0, 0, 0);
            v8bf b1 = *reinterpret_cast<const v8bf*>(&bb[(ks + 1) * 512 + lane * 8]);
            a01 = __builtin_amdgcn_mfma_f32_16x16x32_bf16(a1[0][ks + 1], b1, a01, 0, 0, 0);
            a11 = __builtin_amdgcn_mfma_f32_16x16x32_bf16(a1[1][ks + 1], b1, a11, 0, 0, 0);
        }
        {
            v8bf b0 = *reinterpret_cast<const v8bf*>(&bb[12 * 512 + lane * 8]);
            a00 = __builtin_amdgcn_mfma_f32_16x16x32_bf16(a1[0][12], b0, a00, 0, 0, 0);
            a10 = __builtin_amdgcn_mfma_f32_16x16x32_bf16(a1[1][12], b0, a10, 0, 0, 0);
        }
        float rv = rw2[p * HDIM + n];
#pragma unroll
        for (int i = 0; i < 4; i++) {
            mx0[i] = fmaxf(mx0[i], a00[i] + a01[i] + rv);
            mx1[i] = fmaxf(mx1[i], a10[i] + a11[i] + rv);
        }
        if (p == 15) {
#pragma unroll
            for (int i = 0; i < 4; i++) {
                m1o[(rowb + q * 4 + i) * 224 + n] = f2bf(mx0[i]);
                m1o[(rowb + 16 + q * 4 + i) * 224 + n] = f2bf(mx1[i]);
            }
        }
    }
}

// ---------------- k_m2: m2 = maxpool_p(m1 @ w3.T + b3) -> g_m2 ------------
// Same 128-row/4-wave structure; A = g_m1 (stride 224, zero pads).
__global__ __launch_bounds__(256, 2) void k_m2(
    const float* __restrict__ b3s, const float* __restrict__ b3e) {
    const int bid = blockIdx.x;
    const int net = (bid >> 2) & 1;
    const int r = (bid >> 3) * 4 + (bid & 3);
    const int half = r & 1;
    const int m0 = (r >> 1) * 128;
    const unsigned short* w3 = g_w3bf[net];
    const float* b3 = net ? b3e : b3s;
    unsigned short* m2o = g_m2[net];
    __shared__ __align__(16) unsigned short Bs[2][3584];
    const int tid = threadIdx.x;
    const int lane = tid & 63, wave = tid >> 6;
    const int q = lane >> 4, col = lane & 15, qo = q * 8;
    const int rowb = m0 + wave * 32;
    const int njt = half ? 6 : 7;
    const int T2 = njt * 16;

    v8bf a2[2][7];
#pragma unroll
    for (int s = 0; s < 2; s++) {
        const unsigned short* ap = g_m1[net] + (rowb + s * 16 + col) * 224 + qo;
#pragma unroll
        for (int ks = 0; ks < 7; ks++)
            a2[s][ks] = *reinterpret_cast<const v8bf*>(ap + ks * 32);
    }
    {
        const unsigned short* gb = w3 + (half * 16 + col) * 224 + qo;
        for (int c = wave; c < 7; c += 4) gl_lds16(gb + c * 32, &Bs[0][c * 512]);
    }
    v4f mx0, mx1;
    for (int t = 0; t < T2; t++) {
        __syncthreads();
        if (t + 1 < T2) {
            int jtn = ((t + 1) >> 4) * 2 + half, pn = (t + 1) & 15;
            int j0n = (jtn < 12) ? jtn * 16 : 184;
            const unsigned short* gb = w3 + (pn * HDIM + j0n + col) * 224 + qo;
            unsigned short* lb = Bs[(t + 1) & 1];
            for (int c = wave; c < 7; c += 4) gl_lds16(gb + c * 32, lb + c * 512);
        }
        const unsigned short* bb = Bs[t & 1];
        int jt = (t >> 4) * 2 + half, p = t & 15;
        int j0 = (jt < 12) ? jt * 16 : 184;
        int n = j0 + col;
        if (p == 0) {
            mx0 = (v4f){-INFINITY, -INFINITY, -INFINITY, -INFINITY};
            mx1 = mx0;
        }
        v4f a00 = {0.f, 0.f, 0.f, 0.f}, a01 = a00, a10 = a00, a11 = a00;
#pragma unroll
        for (int ks = 0; ks < 6; ks += 2) {
            v8bf b0 = *reinterpret_cast<const v8bf*>(&bb[ks * 512 + lane * 8]);
            a00 = __builtin_amdgcn_mfma_f32_16x16x32_bf16(a2[0][ks], b0, a00, 0, 0, 0);
            a10 = __builtin_amdgcn_mfma_f32_16x16x32_bf16(a2[1][ks], b0, a10, 0, 0, 0);
            v8bf b1 = *reinterpret_cast<const v8bf*>(&bb[(ks + 1) * 512 + lane * 8]);
            a01 = __builtin_amdgcn_mfma_f32_16x16x32_bf16(a2[0][ks + 1], b1, a01, 0, 0, 0);
            a11 = __builtin_amdgcn_mfma_f32_16x16x32_bf16(a2[1][ks + 1], b1, a11, 0, 0, 0);
        }
        {
            v8bf b0 = *reinterpret_cast<const v8bf*>(&bb[6 * 512 + lane * 8]);
            a00 = __builtin_amdgcn_mfma_f32_16x16x32_bf16(a2[0][6], b0, a00, 0, 0, 0);
            a10 = __builtin_amdgcn_mfma_f32_16x16x32_bf16(a2[1][6], b0, a10, 0, 0, 0);
        }
        float bv = b3[p * HDIM + n];
#pragma unroll
        for (int i = 0; i < 4; i++) {
            mx0[i] = fmaxf(mx0[i], a00[i] + a01[i] + bv);
            mx1[i] = fmaxf(mx1[i], a10[i] + a11[i] + bv);
        }
        if (p == 15) {
#pragma unroll
            for (int i = 0; i < 4; i++) {
                m2o[(rowb + q * 4 + i) * 224 + n] = f2bf(mx0[i]);
                m2o[(rowb + 16 + q * 4 + i) * 224 + n] = f2bf(mx1[i]);
            }
        }
    }
}

// ---------------- k_alpha: max_n([m1|m2] @ w4.T + b4) -> ca/cb ------------
__global__ __launch_bounds__(128) void k_alpha(
    const float* __restrict__ b4s, const float* __restrict__ b4e) {
    const int bid = blockIdx.x;
    const int net = (bid >> 2) & 1;
    const int m0 = ((bid >> 3) * 4 + (bid & 3)) * 64;
    const unsigned short* w4 = g_w4a[net];
    const float* b4 = net ? b4e : b4s;
    float* outv = net ? g_cb : g_ca;
    const int tid = threadIdx.x;
    const int lane = tid & 63, wave = tid >> 6;
    const int q = lane >> 4, col = lane & 15, qo = q * 8;
    const int rowb = m0 + wave * 32;

    v4f ac0 = {0.f, 0.f, 0.f, 0.f}, ac1 = ac0;
#pragma unroll
    for (int half = 0; half < 2; half++) {
        const unsigned short* src = half ? g_m2[net] : g_m1[net];
#pragma unroll
        for (int ks = 0; ks < 7; ks++) {
            v8bf b = *reinterpret_cast<const v8bf*>(&w4[col * 448 + half * 224 + ks * 32 + qo]);
            v8bf x0 = *reinterpret_cast<const v8bf*>(src + (rowb + col) * 224 + ks * 32 + qo);
            ac0 = __builtin_amdgcn_mfma_f32_16x16x32_bf16(x0, b, ac0, 0, 0, 0);
            v8bf x1 = *reinterpret_cast<const v8bf*>(src + (rowb + 16 + col) * 224 + ks * 32 + qo);
            ac1 = __builtin_amdgcn_mfma_f32_16x16x32_bf16(x1, b, ac1, 0, 0, 0);
        }
    }
    float bbi = b4[col];
#pragma unroll
    for (int s = 0; s < 2; s++) {
        v4f ac = s ? ac1 : ac0;
        float v0 = ac[0] + bbi, v1 = ac[1] + bbi, v2 = ac[2] + bbi, v3 = ac[3] + bbi;
        for (int off = 1; off < 16; off <<= 1) {
            v0 = fmaxf(v0, __shfl_xor(v0, off, 16));
            v1 = fmaxf(v1, __shfl_xor(v1, off, 16));
            v2 = fmaxf(v2, __shfl_xor(v2, off, 16));
            v3 = fmaxf(v3, __shfl_xor(v3, off, 16));
        }
        if (col == 0) {
            const int tb = rowb + s * 16 + q * 4;
            outv[tb + 0] = v0;
            outv[tb + 1] = v1;
            outv[tb + 2] = v2;
            outv[tb + 3] = v3;
        }
    }
}

// -------- commit (+inline argmax in block 128): freeze-select & advance ---
__global__ void k_commit(int k, float* __restrict__ out) {
    int done = g_ctrl[k * 3 + 2];
    if (blockIdx.x < 128) {
        int is_beta = blockIdx.x >= 64;
        int t = ((int)blockIdx.x & 63) * 256 + threadIdx.x;
        float* row = out + (is_beta ? 4 * T_LEN : 0) + k * T_LEN;
        if (done) row[t] = row[t - T_LEN];
        else row[t] = (is_beta ? g_cb : g_ca)[t];
    } else {
        __shared__ float sv[256];
        __shared__ int si[256];
        int ns = 0, ne = 0;
        for (int which = 0; which < 2; which++) {
            const float* src = which ? g_cb : g_ca;
            float best = -INFINITY;
            int bi = T_LEN - 1;
            for (int t = threadIdx.x; t < T_LEN; t += 256) {
                float v = src[t];
                if (v > best) { best = v; bi = t; }
            }
            sv[threadIdx.x] = best; si[threadIdx.x] = bi;
            __syncthreads();
            for (int s = 128; s > 0; s >>= 1) {
                if (threadIdx.x < s) {
                    float ov = sv[threadIdx.x + s]; int oi = si[threadIdx.x + s];
                    if (ov > sv[threadIdx.x] || (ov == sv[threadIdx.x] && oi < si[threadIdx.x])) {
                        sv[threadIdx.x] = ov; si[threadIdx.x] = oi;
                    }
                }
                __syncthreads();
            }
            if (which == 0) ns = clampT(si[0]); else ne = clampT(si[0]);
            __syncthreads();
        }
        int t = threadIdx.x;
        if (t < HDIM && !done) { g_h[t] = g_ch[t]; g_c[t] = g_cc[t]; }
        if (t == 0) {
            int sp = g_ctrl[k * 3 + 0], ep = g_ctrl[k * 3 + 1];
            if (done) {
                g_ctrl[(k + 1) * 3 + 0] = sp;
                g_ctrl[(k + 1) * 3 + 1] = ep;
                g_ctrl[(k + 1) * 3 + 2] = 1;
            } else {
                g_ctrl[(k + 1) * 3 + 0] = ns;
                g_ctrl[(k + 1) * 3 + 1] = ne;
                g_ctrl[(k + 1) * 3 + 2] = (k == 0) ? 0 : ((ns == sp && ne == ep) ? 1 : 0);
            }
        }
    }
}

extern "C" void kernel_launch(void* const* d_in, const int* in_sizes, int n_in,
                              void* d_out, int out_size, void* d_ws, size_t ws_size,
                              hipStream_t stream) {
    const float* U    = (const float*)d_in[0];
    const float* Wih  = (const float*)d_in[1];
    const float* Whh  = (const float*)d_in[2];
    const float* bih  = (const float*)d_in[3];
    const float* bhh  = (const float*)d_in[4];
    const float* s_w1 = (const float*)d_in[5];
    const float* s_w2 = (const float*)d_in[6];
    const float* s_b2 = (const float*)d_in[7];
    const float* s_w3 = (const float*)d_in[8];
    const float* s_b3 = (const float*)d_in[9];
    const float* s_w4 = (const float*)d_in[10];
    const float* s_b4 = (const float*)d_in[11];
    const float* e_w1 = (const float*)d_in[12];
    const float* e_w2 = (const float*)d_in[13];
    const float* e_b2 = (const float*)d_in[14];
    const float* e_w3 = (const float*)d_in[15];
    const float* e_b3 = (const float*)d_in[16];
    const float* e_w4 = (const float*)d_in[17];
    const float* e_b4 = (const float*)d_in[18];
    float* out = (float*)d_out;
    (void)d_ws; (void)ws_size; (void)in_sizes; (void)n_in; (void)out_size;

    const int cvt_blocks = (TOT_CH + HDIM + 1 + 255) / 256;
    k_cvt_all<<<cvt_blocks, 256, 0, stream>>>(U, s_w2, e_w2, s_w3, e_w3, s_w4, e_w4);

    for (int k = 0; k < 4; k++) {
        k_gates<<<50, 256, 0, stream>>>(U, Wih, Whh, bih, bhh, k);
        k_r<<<25, 256, 0, stream>>>(U, s_w1, e_w1, k);
        k_rw2<<<400, 256, 0, stream>>>(s_w2, s_b2, e_w2, e_b2);
        k_m1<<<512, 256, 0, stream>>>();
        k_m2<<<512, 256, 0, stream>>>(s_b3, e_b3);
        k_alpha<<<512, 128, 0, stream>>>(s_b4, e_b4);
        k_commit<<<129, 256, 0, stream>>>(k, out);
    }
}